// Round 16
// baseline (251.868 us; speedup 1.0000x reference)
//
#include <hip/hip_runtime.h>
#include <math.h>

// R16 = R15 with ONE bug fixed: tail staging clamp 484 -> 496.
// (float4 = 4 floats; max valid start col = 500-4 = 496. R15's 484 clamp
// corrupted chunk 8's cols 16..19 = x cols 496..499 -> absmax 4.9e-3.)
// Topology (R15): 512 thr = 8 waves -> 2 blocks x 8 = 16 waves/CU = the
// VGPR=80 cap (m69). Waves 0..5: FIR CPW=14, R7-proven predicated codegen.
// Waves 6..7: consumers — stage chunk c+1 (load->ds_write, pf dies before
// scan, R13-proven) then scan chunk c-1 from ybuf[b^1].
// TC=60 (9 chunks: 8*60+20); LDS ~76.7 KB -> 2 blocks/CU.
// One barrier per chunk. YSTRIDE=61 -> conflict-free scan column reads.

#define NTH      512
#define NFIR     384       // 6 FIR waves
#define CPW      14
#define TC       60
#define YSTRIDE  61
#define NCHUNK   9         // 8*60 + 20 = 500
#define TAIL     20
#define T_LEN    500
#define C_OUT    81
#define NITEMS   1200      // 80 rows x 15 float4 per chunk

__global__ __launch_bounds__(NTH)
void snn_ps5_kernel(const float* __restrict__ x,
                    const float* __restrict__ conv_w,
                    const float* __restrict__ conv_b,
                    const float* __restrict__ bn_gamma,
                    const float* __restrict__ bn_beta,
                    const float* __restrict__ bn_mean,
                    const float* __restrict__ bn_var,
                    const float* __restrict__ plif_w,
                    const float* __restrict__ fc_w,
                    const float* __restrict__ fc_b,
                    float* __restrict__ out)
{
    __shared__ float xs[2][80 * TC];           // 2 x 19200 B
    __shared__ float ybuf[2][C_OUT * YSTRIDE]; // 2 x 19764 B
    __shared__ float wsh[64];
    __shared__ float feat[C_OUT];              // total ~76.7 KiB

    const int tid  = threadIdx.x;
    const int n    = blockIdx.x;
    const int lane = tid & 63;
    const float* xn = x + (size_t)n * (80 * T_LEN);

    if (tid < 64) wsh[tid] = conv_w[tid];

    // ---- prologue: stage chunk 0 -> xs[0] (80 rows x 15 float4) ----
    for (int i = tid; i < NITEMS; i += NTH) {
        const int cr = i / 15, t4 = i - cr * 15;
        float4 v4 = *reinterpret_cast<const float4*>(xn + cr * T_LEN + t4 * 4);
        *reinterpret_cast<float4*>(&xs[0][cr * TC + t4 * 4]) = v4;
    }

    // ---- consumer per-lane state (tid 384..511; channel = sid) ----
    float v = 0.0f, cnt = 0.0f, inv_c = 0.0f, bb_c = 0.0f, decay = 0.0f;
    if (tid >= NFIR) {
        const int ch = tid - NFIR;
        decay = 1.0f / (1.0f + expf(-plif_w[0]));
        if (ch < C_OUT) {
            inv_c = bn_gamma[ch] * rsqrtf(bn_var[ch] + 1e-5f);
            bb_c  = conv_b[0] * inv_c + bn_beta[ch] - bn_mean[ch] * inv_c;
        }
    }
    __syncthreads();

    for (int c = 0; c < NCHUNK; ++c) {
        const int b = c & 1;

        if (tid < NFIR) {
            // ========== FIR producers (waves 0..5), R7-proven codegen ======
            const int co0 = (tid >> 6) * CPW;  // 0,14,28,42,56,70
            const float* xsb = xs[b];
            float acc[CPW];
            float win[CPW];                    // win[(k+r)%CPW] = row co0+k+r-32
            #pragma unroll
            for (int r = 0; r < CPW; ++r) acc[r] = 0.0f;
            const int row0 = co0 - 32;
            #pragma unroll
            for (int m = 0; m < CPW - 1; ++m) {
                const int row = row0 + m;      // wave-uniform -> scalar branch
                win[m] = ((unsigned)row < 80u) ? xsb[row * TC + lane] : 0.0f;
            }
            #pragma unroll
            for (int k = 0; k < 64; ++k) {
                const int row = row0 + k + (CPW - 1);
                win[(k + CPW - 1) % CPW] =
                    ((unsigned)row < 80u) ? xsb[row * TC + lane] : 0.0f;
                const float wk = wsh[k];       // LDS broadcast
                #pragma unroll
                for (int r = 0; r < CPW; ++r)
                    acc[r] = fmaf(wk, win[(k + r) % CPW], acc[r]);
            }
            if (lane < TC) {
                #pragma unroll
                for (int r = 0; r < CPW; ++r) {
                    const int co = co0 + r;
                    if (co < C_OUT) ybuf[b][co * YSTRIDE + lane] = acc[r];
                }
            }
        } else {
            // ========== consumers: stage (load->ds_write) then scan ========
            const int sid = tid - NFIR;        // 0..127

            if (c < NCHUNK - 1) {
                const int t0n = (c + 1) * TC;
                float4 pf[10];
                #pragma unroll
                for (int s = 0; s < 10; ++s) {
                    const int i = s * 128 + sid;        // 0..1279
                    if (i < NITEMS) {
                        const int cr = i / 15, t4 = i - cr * 15;
                        int toff = t0n + t4 * 4;
                        if (toff > 496) toff = 496;     // float4 = 4 floats; max start 496
                        pf[s] = *reinterpret_cast<const float4*>(xn + cr * T_LEN + toff);
                    }
                }
                #pragma unroll
                for (int s = 0; s < 10; ++s) {
                    const int i = s * 128 + sid;
                    if (i < NITEMS) {
                        const int cr = i / 15, t4 = i - cr * 15;
                        *reinterpret_cast<float4*>(&xs[b ^ 1][cr * TC + t4 * 4]) = pf[s];
                    }
                }
            }

            // PLIF scan of chunk c-1 (60 cols; chunk 8 tail in epilogue)
            if (c > 0 && sid < C_OUT) {
                const float* yrow = &ybuf[b ^ 1][sid * YSTRIDE];
                #pragma unroll 4
                for (int t = 0; t < TC; ++t) {
                    const float xt = fmaf(yrow[t], inv_c, bb_c);   // BN
                    v = fmaf(xt - v, decay, v);                    // v += (x-v)*decay
                    const bool s = (v >= 1.0f);
                    cnt += s ? 1.0f : 0.0f;
                    v = s ? 0.0f : v;
                }
            }
        }
        __syncthreads();   // single barrier per chunk
    }

    // ---- epilogue: scan chunk 8 (20 cols) from ybuf[0] ----
    if (tid >= NFIR) {
        const int sid = tid - NFIR;
        if (sid < C_OUT) {
            const float* yrow = &ybuf[0][sid * YSTRIDE];
            #pragma unroll 4
            for (int t = 0; t < TAIL; ++t) {
                const float xt = fmaf(yrow[t], inv_c, bb_c);
                v = fmaf(xt - v, decay, v);
                const bool s = (v >= 1.0f);
                cnt += s ? 1.0f : 0.0f;
                v = s ? 0.0f : v;
            }
            feat[sid] = cnt * (1.0f / 500.0f);
        }
    }
    __syncthreads();

    if (tid < 3) {
        float o = fc_b[tid];
        #pragma unroll 3
        for (int cc = 0; cc < C_OUT; ++cc)
            o = fmaf(feat[cc], fc_w[tid * C_OUT + cc], o);
        out[n * 3 + tid] = o;
    }
}

extern "C" void kernel_launch(void* const* d_in, const int* in_sizes, int n_in,
                              void* d_out, int out_size, void* d_ws, size_t ws_size,
                              hipStream_t stream)
{
    const float* x        = (const float*)d_in[0];
    const float* conv_w   = (const float*)d_in[1];
    const float* conv_b   = (const float*)d_in[2];
    const float* bn_gamma = (const float*)d_in[3];
    const float* bn_beta  = (const float*)d_in[4];
    const float* bn_mean  = (const float*)d_in[5];
    const float* bn_var   = (const float*)d_in[6];
    const float* plif_w   = (const float*)d_in[7];
    const float* fc_w     = (const float*)d_in[8];
    const float* fc_b     = (const float*)d_in[9];
    float* out            = (float*)d_out;

    snn_ps5_kernel<<<1024, NTH, 0, stream>>>(
        x, conv_w, conv_b, bn_gamma, bn_beta, bn_mean, bn_var,
        plif_w, fc_w, fc_b, out);
}

// Round 17
// 112.001 us; speedup vs baseline: 2.2488x; 2.2488x over previous
//
#include <hip/hip_runtime.h>
#include <math.h>

// R17 = R13's producer/consumer topology, rebalanced: 832 thr = 13 waves.
//   waves 0..8 : FIR, CPW=9 -> 9x9 = 81 channel slots EXACTLY (no waste).
//                Padded xs (rows 0..31,112..143 zero) -> pure ds_read+fma.
//                win+acc = 18 regs: far under every unroll/VGPR cliff.
//   waves 9..12: consumers. Stage chunk c+1: pf[5] (half R13's pf[10]
//                pressure) load -> ds_write (pf dies before scan, R13-proven)
//                -> scan chunk c-1 (sid<81) from ybuf[b^1].
// All indexing power-of-2 (R16 lesson: div-by-15 + guarded pf -> VGPR 128 +
// spill). Dbuf xs+ybuf, ONE barrier/chunk, TC=64, 8 chunks (7*64+52).
// LDS = xs 2*144*64*4 (73728) + ybuf 2*81*65*4 (42120) + wsh + feat
//     ~ 113.7 KB -> 1 block/CU (accepted); waves/SIMD 2.5 -> 3.25 for
// ds_read->FMA latency interleave (R13 VALUBusy 63% = the gap).

#define NTH      832
#define NFIR     576       // 9 FIR waves
#define CPW      9
#define TC       64
#define XROWS    144       // max padded row read = 72 + 8 + 63 = 143
#define YSTRIDE  65        // +1 pad: conflict-free scan column reads
#define NCHUNK   8         // 7*64 + 52 = 500
#define TAIL     52
#define T_LEN    500
#define C_OUT    81

__global__ __launch_bounds__(NTH)
void snn_ps6_kernel(const float* __restrict__ x,
                    const float* __restrict__ conv_w,
                    const float* __restrict__ conv_b,
                    const float* __restrict__ bn_gamma,
                    const float* __restrict__ bn_beta,
                    const float* __restrict__ bn_mean,
                    const float* __restrict__ bn_var,
                    const float* __restrict__ plif_w,
                    const float* __restrict__ fc_w,
                    const float* __restrict__ fc_b,
                    float* __restrict__ out)
{
    __shared__ float xs[2][XROWS * TC];        // 2 x 36864 B
    __shared__ float ybuf[2][C_OUT * YSTRIDE]; // 2 x 21060 B
    __shared__ float wsh[64];
    __shared__ float feat[C_OUT];              // total ~113.7 KiB

    const int tid  = threadIdx.x;
    const int n    = blockIdx.x;
    const int lane = tid & 63;
    const float* xn = x + (size_t)n * (80 * T_LEN);

    if (tid < 64) wsh[tid] = conv_w[tid];

    // ---- zero FIR pad rows of BOTH buffers (written once) ----
    for (int i = tid; i < 32 * TC; i += NTH) {
        xs[0][i] = 0.0f;             xs[1][i] = 0.0f;              // rows 0..31
        xs[0][112 * TC + i] = 0.0f;  xs[1][112 * TC + i] = 0.0f;   // rows 112..143
    }
    // ---- stage chunk 0 -> xs[0] rows 32..111 (80 rows x 16 float4) ----
    for (int i = tid; i < 1280; i += NTH) {
        const int cr = i >> 4, t4 = i & 15;
        float4 v4 = *reinterpret_cast<const float4*>(xn + cr * T_LEN + t4 * 4);
        *reinterpret_cast<float4*>(&xs[0][(cr + 32) * TC + t4 * 4]) = v4;
    }

    // ---- consumer per-lane state (tid 576..831; channel = sid) ----
    const int sid = tid - NFIR;                // <0 for FIR threads
    float v = 0.0f, cnt = 0.0f, inv_c = 0.0f, bb_c = 0.0f, decay = 0.0f;
    if (tid >= NFIR) {
        decay = 1.0f / (1.0f + expf(-plif_w[0]));
        const int ch = (sid < C_OUT) ? sid : 0;
        inv_c = bn_gamma[ch] * rsqrtf(bn_var[ch] + 1e-5f);
        bb_c  = conv_b[0] * inv_c + bn_beta[ch] - bn_mean[ch] * inv_c;
    }
    __syncthreads();

    for (int c = 0; c < NCHUNK; ++c) {
        const int b = c & 1;

        if (tid < NFIR) {
            // ========== FIR producers (waves 0..8): 9 channels each ========
            const int co0 = (tid >> 6) * CPW;  // 0,9,...,72
            const float* xsb = xs[b];
            float acc[CPW];
            float win[CPW];                    // win[(k+r)%CPW] = padded row co0+k+r
            #pragma unroll
            for (int r = 0; r < CPW; ++r) acc[r] = 0.0f;
            const int base = co0 * TC + lane;
            #pragma unroll
            for (int m = 0; m < CPW - 1; ++m) win[m] = xsb[base + m * TC];
            #pragma unroll
            for (int k = 0; k < 64; ++k) {
                win[(k + CPW - 1) % CPW] = xsb[base + (k + CPW - 1) * TC];
                const float wk = wsh[k];       // LDS broadcast
                #pragma unroll
                for (int r = 0; r < CPW; ++r)
                    acc[r] = fmaf(wk, win[(k + r) % CPW], acc[r]);
            }
            #pragma unroll
            for (int r = 0; r < CPW; ++r) {
                const int co = co0 + r;        // max 80 < 81: full coverage
                if (co < C_OUT) ybuf[b][co * YSTRIDE + lane] = acc[r];
            }
        } else {
            // ===== consumers (waves 9..12): stage load->ds_write, then scan =====
            if (c < NCHUNK - 1) {
                const int t0n = (c + 1) * TC;
                float4 pf[5];
                #pragma unroll
                for (int s = 0; s < 5; ++s) {
                    const int i  = s * 256 + sid;   // 1280 items over 256 threads
                    const int cr = i >> 4, t4 = i & 15;
                    int toff = t0n + t4 * 4;
                    if (toff > 496) toff = 496;     // float4: max start = 500-4
                    pf[s] = *reinterpret_cast<const float4*>(xn + cr * T_LEN + toff);
                }
                #pragma unroll
                for (int s = 0; s < 5; ++s) {
                    const int i  = s * 256 + sid;
                    const int cr = i >> 4, t4 = i & 15;
                    *reinterpret_cast<float4*>(&xs[b ^ 1][(cr + 32) * TC + t4 * 4]) = pf[s];
                }
            }

            // PLIF scan of chunk c-1 (64 cols; chunk 7 in epilogue)
            if (c > 0 && sid < C_OUT) {
                const float* yrow = &ybuf[b ^ 1][sid * YSTRIDE];
                #pragma unroll 4
                for (int t = 0; t < TC; ++t) {
                    const float xt = fmaf(yrow[t], inv_c, bb_c);   // BN
                    v = fmaf(xt - v, decay, v);                    // v += (x-v)*decay
                    const bool s = (v >= 1.0f);
                    cnt += s ? 1.0f : 0.0f;
                    v = s ? 0.0f : v;
                }
            }
        }
        __syncthreads();   // single barrier per chunk
    }

    // ---- epilogue: scan chunk 7 (52 cols) from ybuf[1] ----
    if (tid >= NFIR && sid < C_OUT) {
        const float* yrow = &ybuf[1][sid * YSTRIDE];
        #pragma unroll 4
        for (int t = 0; t < TAIL; ++t) {
            const float xt = fmaf(yrow[t], inv_c, bb_c);
            v = fmaf(xt - v, decay, v);
            const bool s = (v >= 1.0f);
            cnt += s ? 1.0f : 0.0f;
            v = s ? 0.0f : v;
        }
        feat[sid] = cnt * (1.0f / 500.0f);
    }
    __syncthreads();

    if (tid < 3) {
        float o = fc_b[tid];
        #pragma unroll 3
        for (int cc = 0; cc < C_OUT; ++cc)
            o = fmaf(feat[cc], fc_w[tid * C_OUT + cc], o);
        out[n * 3 + tid] = o;
    }
}

extern "C" void kernel_launch(void* const* d_in, const int* in_sizes, int n_in,
                              void* d_out, int out_size, void* d_ws, size_t ws_size,
                              hipStream_t stream)
{
    const float* x        = (const float*)d_in[0];
    const float* conv_w   = (const float*)d_in[1];
    const float* conv_b   = (const float*)d_in[2];
    const float* bn_gamma = (const float*)d_in[3];
    const float* bn_beta  = (const float*)d_in[4];
    const float* bn_mean  = (const float*)d_in[5];
    const float* bn_var   = (const float*)d_in[6];
    const float* plif_w   = (const float*)d_in[7];
    const float* fc_w     = (const float*)d_in[8];
    const float* fc_b     = (const float*)d_in[9];
    float* out            = (float*)d_out;

    snn_ps6_kernel<<<1024, NTH, 0, stream>>>(
        x, conv_w, conv_b, bn_gamma, bn_beta, bn_mean, bn_var,
        plif_w, fc_w, fc_b, out);
}